// Round 7
// baseline (57.132 us; speedup 1.0000x reference)
//
#include <hip/hip_runtime.h>
#include <math.h>

// ws layout (float offsets) — every slot written fresh each call, no atomics
#define WS_FOCALP 0        // 2048 focal block partials
#define WS_CONSP  2048     // 6*2048 consensus partials, [k][b]
#define WS_AREAP  14336    // 512 (img*16+part)
#define WS_EXP_   14848    // 512
#define WS_EYP_   15360    // 512
#define WS_POS    15872    // 1024
#define WS_PART   16896    // 1024*32 float2 (m,s) -> 65536 floats (ends 82432)
// bf16 planes (byte offsets into ws): row-major [1024][512] bf16 = 1 MB each
#define WS_HI_B   393216
#define WS_LO_B   1441792

typedef __attribute__((ext_vector_type(8))) short bf16x8;
typedef __attribute__((ext_vector_type(4))) float f32x4;

__device__ inline float wave_reduce(float v) {
#pragma unroll
  for (int m = 32; m >= 1; m >>= 1) v += __shfl_xor(v, m);
  return v;
}

__device__ inline unsigned short bf16_rne(float x) {
  union { float f; unsigned u; } v; v.f = x;
  unsigned r = v.u + 0x7FFF + ((v.u >> 16) & 1);
  return (unsigned short)(r >> 16);
}
__device__ inline float bf16_f(unsigned short h) {
  union { unsigned u; float f; } v; v.u = ((unsigned)h) << 16; return v.f;
}

__device__ inline float focal_px(float v0, float v1, float v2, float v3,
                                 float v4, float v5, float v6, float v7, int tt) {
  float mx = fmaxf(fmaxf(fmaxf(v0, v1), fmaxf(v2, v3)),
                   fmaxf(fmaxf(v4, v5), fmaxf(v6, v7)));
  float se = __expf(v0 - mx) + __expf(v1 - mx) + __expf(v2 - mx) + __expf(v3 - mx) +
             __expf(v4 - mx) + __expf(v5 - mx) + __expf(v6 - mx) + __expf(v7 - mx);
  float xt = v0;
  xt = (tt == 1) ? v1 : xt;
  xt = (tt == 2) ? v2 : xt;
  xt = (tt == 3) ? v3 : xt;
  xt = (tt == 4) ? v4 : xt;
  xt = (tt == 5) ? v5 : xt;
  xt = (tt == 6) ? v6 : xt;
  xt = (tt == 7) ? v7 : xt;
  float lp = (xt - mx) - __logf(se);
  float p = __expf(lp);
  float om = 1.0f - p;
  return 0.25f * om * om * (-lp);
}

// ---------- mega: streaming only ----------
// blocks [0,2048): focal | [2048,2560): circularity | [2560,4608): consensus
// [4608,4864): prep — feature norms + normalized bf16 hi/lo split emit
__global__ __launch_bounds__(256) void mega_kernel(
    const float* __restrict__ logits, const int* __restrict__ target,
    const float* __restrict__ feat, const float* __restrict__ masks,
    const float* __restrict__ preds, float* __restrict__ ws) {
  __shared__ float red[32];
  const int bid = blockIdx.x;
  const int tid = threadIdx.x;
  const int lane = tid & 63;
  const int wid = tid >> 6;

  if (bid < 2048) {
    // ---------------- focal ----------------
    int t = bid * 256 + tid;
    int p4 = t * 4;
    int b = p4 >> 16;
    int hw = p4 & 65535;
    const float* lb = logits + (b << 19) + hw;
    float4 x0 = *(const float4*)(lb + (0 << 16));
    float4 x1 = *(const float4*)(lb + (1 << 16));
    float4 x2 = *(const float4*)(lb + (2 << 16));
    float4 x3 = *(const float4*)(lb + (3 << 16));
    float4 x4 = *(const float4*)(lb + (4 << 16));
    float4 x5 = *(const float4*)(lb + (5 << 16));
    float4 x6 = *(const float4*)(lb + (6 << 16));
    float4 x7 = *(const float4*)(lb + (7 << 16));
    int4 tg = *(const int4*)(target + p4);
    float acc = 0.0f;
    acc += focal_px(x0.x, x1.x, x2.x, x3.x, x4.x, x5.x, x6.x, x7.x, tg.x);
    acc += focal_px(x0.y, x1.y, x2.y, x3.y, x4.y, x5.y, x6.y, x7.y, tg.y);
    acc += focal_px(x0.z, x1.z, x2.z, x3.z, x4.z, x5.z, x6.z, x7.z, tg.z);
    acc += focal_px(x0.w, x1.w, x2.w, x3.w, x4.w, x5.w, x6.w, x7.w, tg.w);
    float v = wave_reduce(acc);
    if (lane == 0) red[wid] = v;
    __syncthreads();
    if (tid == 0) ws[WS_FOCALP + bid] = red[0] + red[1] + red[2] + red[3];

  } else if (bid < 2560) {
    // ---------------- circularity ----------------
    int bi = bid - 2048;
    int img = bi >> 4;
    int part = bi & 15;
    const float* mS = masks + img * 3 * 65536;
    const float4* m4 = (const float4*)mS;
    float a = 0.0f, ex = 0.0f, ey = 0.0f;
#pragma unroll
    for (int i = 0; i < 4; i++) {
      int v = tid + 256 * i;
      int rl = v >> 6;
      int c4 = v & 63;
      int row = part * 16 + rl;
      float4 val = m4[row * 64 + c4];
      a += val.x + val.y + val.z + val.w;
      ey += fabsf(val.y - val.x) + fabsf(val.z - val.y) + fabsf(val.w - val.z);
      if (c4 > 0) ey += fabsf(val.x - mS[row * 256 + c4 * 4 - 1]);
      if (row > 0) {
        float4 u = m4[(row - 1) * 64 + c4];
        ex += fabsf(val.x - u.x) + fabsf(val.y - u.y) +
              fabsf(val.z - u.z) + fabsf(val.w - u.w);
      }
    }
    float ra = wave_reduce(a);
    float rx = wave_reduce(ex);
    float ry = wave_reduce(ey);
    if (lane == 0) {
      red[wid + 0] = ra; red[wid + 4] = rx; red[wid + 8] = ry;
    }
    __syncthreads();
    if (tid == 0) {
      ws[WS_AREAP + bi] = red[0] + red[1] + red[2] + red[3];
      ws[WS_EXP_ + bi] = red[4] + red[5] + red[6] + red[7];
      ws[WS_EYP_ + bi] = red[8] + red[9] + red[10] + red[11];
    }

  } else if (bid < 4608) {
    // ---------------- consensus ----------------
    int b = bid - 2560;
    int t = b * 256 + tid;
    const float4* q = (const float4*)preds;
    float4 a0 = q[t];
    float4 a1 = q[t + 524288];
    float4 a2 = q[t + 1048576];
    float s0 = a0.x + a0.y + a0.z + a0.w;
    float s1 = a1.x + a1.y + a1.z + a1.w;
    float s2 = a2.x + a2.y + a2.z + a2.w;
    float p01 = a0.x * a1.x + a0.y * a1.y + a0.z * a1.z + a0.w * a1.w;
    float p02 = a0.x * a2.x + a0.y * a2.y + a0.z * a2.z + a0.w * a2.w;
    float p12 = a1.x * a2.x + a1.y * a2.y + a1.z * a2.z + a1.w * a2.w;
    float r0 = wave_reduce(s0);
    float r1 = wave_reduce(s1);
    float r2 = wave_reduce(s2);
    float r3 = wave_reduce(p01);
    float r4 = wave_reduce(p02);
    float r5 = wave_reduce(p12);
    if (lane == 0) {
      red[wid + 0] = r0; red[wid + 4] = r1; red[wid + 8] = r2;
      red[wid + 12] = r3; red[wid + 16] = r4; red[wid + 20] = r5;
    }
    __syncthreads();
    if (tid == 0) {
#pragma unroll
      for (int k = 0; k < 6; k++)
        ws[WS_CONSP + k * 2048 + b] =
            red[k * 4] + red[k * 4 + 1] + red[k * 4 + 2] + red[k * 4 + 3];
    }

  } else {
    // ---------------- prep: norms + bf16 hi/lo emit ----------------
    int row = (bid - 4608) * 4 + wid;  // 0..1023
    const float4* f4 = (const float4*)feat;
    float4 u = f4[row * 128 + lane];
    float4 w = f4[row * 128 + 64 + lane];
    float s = u.x * u.x + u.y * u.y + u.z * u.z + u.w * u.w +
              w.x * w.x + w.y * w.y + w.z * w.z + w.w * w.w;
    s = wave_reduce(s);
    // scale = (1/|f|) * sqrt(1/0.07) so that g.g^T == sim/T directly
    float scale = 3.7796447300922719f / sqrtf(s);
    float g[8] = {u.x * scale, u.y * scale, u.z * scale, u.w * scale,
                  w.x * scale, w.y * scale, w.z * scale, w.w * scale};
    unsigned short h[8];
    unsigned short l[8];
#pragma unroll
    for (int i = 0; i < 8; i++) {
      h[i] = bf16_rne(g[i]);
      l[i] = bf16_rne(g[i] - bf16_f(h[i]));
    }
    char* hb = (char*)ws + WS_HI_B + row * 1024;
    char* lb = (char*)ws + WS_LO_B + row * 1024;
    *(ushort4*)(hb + lane * 8) = make_ushort4(h[0], h[1], h[2], h[3]);
    *(ushort4*)(hb + 512 + lane * 8) = make_ushort4(h[4], h[5], h[6], h[7]);
    *(ushort4*)(lb + lane * 8) = make_ushort4(l[0], l[1], l[2], l[3]);
    *(ushort4*)(lb + 512 + lane * 8) = make_ushort4(l[4], l[5], l[6], l[7]);
  }
}

// ---------- sim: LDS-free register MFMA, planes exclusively L2-resident ----
// 256 blocks = 16 rt x 16 ct, tile 64x64; 4 waves (2x2), 32x32 per wave.
// K=512; per k-step: 8 loads (ah2,al2,bh2,bl2) + 12 MFMAs (hh,hl,lh).
// Fused per-row (m,s) LSE partials over 32-col groups -> WS_PART[1024][32].
__global__ __launch_bounds__(256) void sim_kernel(float* __restrict__ ws) {
  const int tid = threadIdx.x;
  const int lane = tid & 63;
  const int wid = tid >> 6;
  const int rt = blockIdx.x >> 4, ct = blockIdx.x & 15;
  const int wr = wid >> 1, wc = wid & 1;
  const int l15 = lane & 15;
  const int hi8 = lane >> 4;
  const char* HI = (const char*)ws + WS_HI_B;
  const char* LO = (const char*)ws + WS_LO_B;
  const int ar = rt * 64 + wr * 32 + l15;  // + r*16
  const int bc = ct * 64 + wc * 32 + l15;  // + c*16
  const int kb16 = hi8 * 16;               // byte offset within 64B k-chunk

  f32x4 acc[2][2];
#pragma unroll
  for (int r = 0; r < 2; r++)
#pragma unroll
    for (int c = 0; c < 2; c++) acc[r][c] = (f32x4){0.f, 0.f, 0.f, 0.f};

#pragma unroll 4
  for (int kb = 0; kb < 16; kb++) {
    int ko = kb * 64 + kb16;
    bf16x8 ah[2], al[2], bh[2], bl[2];
#pragma unroll
    for (int r = 0; r < 2; r++) {
      ah[r] = *(const bf16x8*)(HI + (ar + r * 16) * 1024 + ko);
      al[r] = *(const bf16x8*)(LO + (ar + r * 16) * 1024 + ko);
    }
#pragma unroll
    for (int c = 0; c < 2; c++) {
      bh[c] = *(const bf16x8*)(HI + (bc + c * 16) * 1024 + ko);
      bl[c] = *(const bf16x8*)(LO + (bc + c * 16) * 1024 + ko);
    }
#pragma unroll
    for (int r = 0; r < 2; r++)
#pragma unroll
      for (int c = 0; c < 2; c++) {
        acc[r][c] = __builtin_amdgcn_mfma_f32_16x16x32_bf16(ah[r], bh[c], acc[r][c], 0, 0, 0);
        acc[r][c] = __builtin_amdgcn_mfma_f32_16x16x32_bf16(ah[r], bl[c], acc[r][c], 0, 0, 0);
        acc[r][c] = __builtin_amdgcn_mfma_f32_16x16x32_bf16(al[r], bh[c], acc[r][c], 0, 0, 0);
      }
  }

  // epilogue: per tile, D row=(lane>>4)*4+q, col=lane&15
  float2* part = (float2*)(ws + WS_PART);
#pragma unroll
  for (int r = 0; r < 2; r++)
#pragma unroll
    for (int q = 0; q < 4; q++) {
      int row = rt * 64 + wr * 32 + r * 16 + hi8 * 4 + q;
      int pc = (row + 512) & 1023;
      float m = -3e38f;
      float v[2];
#pragma unroll
      for (int c = 0; c < 2; c++) {
        int col = ct * 64 + wc * 32 + c * 16 + l15;
        float x = acc[r][c][q];
        if (col == pc) ws[WS_POS + row] = x;
        if (col == row) x = -1e30f;
        v[c] = x;
        m = fmaxf(m, x);
      }
      float s = __expf(v[0] - m) + __expf(v[1] - m);
#pragma unroll
      for (int d = 1; d < 16; d <<= 1) {
        float mo = __shfl_xor(m, d), so = __shfl_xor(s, d);
        float nm = fmaxf(m, mo);
        s = s * __expf(m - nm) + so * __expf(mo - nm);
        m = nm;
      }
      if (l15 == 0) part[row * 32 + ct * 2 + wc] = make_float2(m, s);
    }
}

__global__ __launch_bounds__(1024) void final_kernel(float* __restrict__ ws,
                                                     float* __restrict__ out) {
  __shared__ float red[16][8];
  __shared__ float li_s[32];
  int r = threadIdx.x;  // 0..1023
  int lane = r & 63, wid = r >> 6;

  float v[8];
  // ---- contrastive LSE merge over 32 col-groups ----
  const float2* part = (const float2*)(ws + WS_PART);
  float M = -1e30f, S = 0.0f;
#pragma unroll
  for (int ctl = 0; ctl < 32; ctl++) {
    float2 p = part[r * 32 + ctl];
    float nm = fmaxf(M, p.x);
    S = S * __expf(M - nm) + p.y * __expf(p.x - nm);
    M = nm;
  }
  v[0] = (M + __logf(S)) - ws[WS_POS + r];
  // ---- focal partials ----
  v[1] = ws[WS_FOCALP + r] + ws[WS_FOCALP + r + 1024];
  // ---- consensus partials ----
#pragma unroll
  for (int k = 0; k < 6; k++) {
    const float* p = ws + WS_CONSP + k * 2048;
    v[2 + k] = p[r] + p[r + 1024];
  }
#pragma unroll
  for (int k = 0; k < 8; k++) {
    v[k] = wave_reduce(v[k]);
    if (lane == 0) red[wid][k] = v[k];
  }

  // ---- circularity: 32 imgs x 16 parts ----
  if (r < 512) {
    float a = ws[WS_AREAP + r];
    float ex = ws[WS_EXP_ + r];
    float ey = ws[WS_EYP_ + r];
#pragma unroll
    for (int d = 1; d < 16; d <<= 1) {
      a += __shfl_xor(a, d);
      ex += __shfl_xor(ex, d);
      ey += __shfl_xor(ey, d);
    }
    if ((r & 15) == 0) {
      float per = ex + ey;
      float dd = fmaxf(per, 1e-12f);
      float c = 12.566370614359172f * a / (dd * dd);
      li_s[r >> 4] = (a > 0.0f && per > 0.0f) ? (c - 1.0f) * (c - 1.0f) : 0.0f;
    }
  }
  __syncthreads();

  if (r == 0) {
    float tot[8];
#pragma unroll
    for (int k = 0; k < 8; k++) {
      float t = 0.0f;
#pragma unroll
      for (int i = 0; i < 16; i++) t += red[i][k];
      tot[k] = t;
    }
    float circ = 0.0f;
#pragma unroll
    for (int i = 0; i < 32; i++) circ += li_s[i];
    circ = 0.1f * circ / 32.0f;

    float contr = tot[0] / 1024.0f;
    float focal = tot[1] / 2097152.0f;

    float S0 = tot[2], S1 = tot[3], S2 = tot[4];
    float P01 = tot[5], P02 = tot[6], P12 = tot[7];
    float co = 0.0f;
    co += fmaxf(0.6f - P01 / (S0 + S1 - P01 + 1e-6f), 0.0f);
    co += fmaxf(0.6f - P02 / (S0 + S2 - P02 + 1e-6f), 0.0f);
    co += fmaxf(0.6f - P12 / (S1 + S2 - P12 + 1e-6f), 0.0f);
    co *= (1.0f / 3.0f);

    out[0] = focal + 0.5f * contr + circ + 0.3f * co;
  }
}

extern "C" void kernel_launch(void* const* d_in, const int* in_sizes, int n_in,
                              void* d_out, int out_size, void* d_ws, size_t ws_size,
                              hipStream_t stream) {
  const float* logits = (const float*)d_in[0];
  const int* target = (const int*)d_in[1];
  const float* feat = (const float*)d_in[2];
  const float* masks = (const float*)d_in[3];
  const float* preds = (const float*)d_in[4];
  float* ws = (float*)d_ws;
  float* out = (float*)d_out;

  mega_kernel<<<4864, 256, 0, stream>>>(logits, target, feat, masks, preds, ws);
  sim_kernel<<<256, 256, 0, stream>>>(ws);
  final_kernel<<<1, 1024, 0, stream>>>(ws, out);
}

// Round 8
// 47.196 us; speedup vs baseline: 1.2105x; 1.2105x over previous
//
#include <hip/hip_runtime.h>
#include <math.h>

// ws layout (float offsets) — every slot written fresh each call, no atomics
#define WS_FOCALP 0        // 2048 focal block partials
#define WS_CONSP  2048     // 6*2048 consensus partials, [k][b]
#define WS_AREAP  14336    // 512 (img*16+part)
#define WS_EXP_   14848    // 512
#define WS_EYP_   15360    // 512
#define WS_POS    15872    // 1024
#define WS_PART   16896    // 1024*32 float2 (m,s) -> 65536 floats (ends 82432)
// bf16 planes (byte offsets into ws), FRAGMENT-TILED:
//   plane = [rg(64)][kb(16)] tiles; tile = 1KB; byte l*16 of tile = fragment
//   of lane l: row rg*16+(l&15), k = kb*32+(l>>4)*8 .. +7.
#define WS_HI_B   393216
#define WS_LO_B   1441792

typedef __attribute__((ext_vector_type(8))) short bf16x8;
typedef __attribute__((ext_vector_type(4))) float f32x4;

__device__ inline float wave_reduce(float v) {
#pragma unroll
  for (int m = 32; m >= 1; m >>= 1) v += __shfl_xor(v, m);
  return v;
}

__device__ inline unsigned short bf16_rne(float x) {
  union { float f; unsigned u; } v; v.f = x;
  unsigned r = v.u + 0x7FFF + ((v.u >> 16) & 1);
  return (unsigned short)(r >> 16);
}
__device__ inline float bf16_f(unsigned short h) {
  union { unsigned u; float f; } v; v.u = ((unsigned)h) << 16; return v.f;
}

__device__ inline float focal_px(float v0, float v1, float v2, float v3,
                                 float v4, float v5, float v6, float v7, int tt) {
  float mx = fmaxf(fmaxf(fmaxf(v0, v1), fmaxf(v2, v3)),
                   fmaxf(fmaxf(v4, v5), fmaxf(v6, v7)));
  float se = __expf(v0 - mx) + __expf(v1 - mx) + __expf(v2 - mx) + __expf(v3 - mx) +
             __expf(v4 - mx) + __expf(v5 - mx) + __expf(v6 - mx) + __expf(v7 - mx);
  float xt = v0;
  xt = (tt == 1) ? v1 : xt;
  xt = (tt == 2) ? v2 : xt;
  xt = (tt == 3) ? v3 : xt;
  xt = (tt == 4) ? v4 : xt;
  xt = (tt == 5) ? v5 : xt;
  xt = (tt == 6) ? v6 : xt;
  xt = (tt == 7) ? v7 : xt;
  float lp = (xt - mx) - __logf(se);
  float p = __expf(lp);
  float om = 1.0f - p;
  return 0.25f * om * om * (-lp);
}

// ---------- prep: norms + normalized bf16 hi/lo split, FRAGMENT-TILED ------
__global__ __launch_bounds__(256) void prep_kernel(const float* __restrict__ feat,
                                                   float* __restrict__ ws) {
  const int tid = threadIdx.x;
  const int lane = tid & 63;
  const int wid = tid >> 6;
  int row = blockIdx.x * 4 + wid;  // 0..1023
  const float4* f4 = (const float4*)feat;
  float4 u = f4[row * 128 + lane];   // k = 4*lane .. +3
  float4 w = f4[row * 128 + 64 + lane];  // k = 256+4*lane .. +3
  float s = u.x * u.x + u.y * u.y + u.z * u.z + u.w * u.w +
            w.x * w.x + w.y * w.y + w.z * w.z + w.w * w.w;
  s = wave_reduce(s);
  // scale = (1/|f|) * sqrt(1/0.07) so that g.g^T == sim/T directly
  float scale = 3.7796447300922719f / sqrtf(s);
  float g[8] = {u.x * scale, u.y * scale, u.z * scale, u.w * scale,
                w.x * scale, w.y * scale, w.z * scale, w.w * scale};
  unsigned short h[8];
  unsigned short l[8];
#pragma unroll
  for (int i = 0; i < 8; i++) {
    h[i] = bf16_rne(g[i]);
    l[i] = bf16_rne(g[i] - bf16_f(h[i]));
  }
  // tiled addresses: elem (row,k) -> tile(row>>4, k>>5)*1KB
  //   + slot(((k>>3)&3)*16 + (row&15))*16 + (k&7)*2
  const int rg = row >> 4, r15 = row & 15;
  int k0 = lane * 4;
  int k1 = 256 + lane * 4;
  int off0 = (rg * 16 + (k0 >> 5)) * 1024 + (((k0 >> 3) & 3) * 16 + r15) * 16 + (k0 & 7) * 2;
  int off1 = (rg * 16 + (k1 >> 5)) * 1024 + (((k1 >> 3) & 3) * 16 + r15) * 16 + (k1 & 7) * 2;
  char* hb = (char*)ws + WS_HI_B;
  char* lb = (char*)ws + WS_LO_B;
  *(ushort4*)(hb + off0) = make_ushort4(h[0], h[1], h[2], h[3]);
  *(ushort4*)(hb + off1) = make_ushort4(h[4], h[5], h[6], h[7]);
  *(ushort4*)(lb + off0) = make_ushort4(l[0], l[1], l[2], l[3]);
  *(ushort4*)(lb + off1) = make_ushort4(l[4], l[5], l[6], l[7]);
}

// ---------- fused ----------
// blocks [0,512): sim — LDS-free register MFMA from fragment-tiled planes.
//   Grid 32 rt x 16 ct; tile 32x64; 4 waves (2x2): wave = 16 rows x 32 cols.
//   Per k-step per wave: 6 perfectly-coalesced 1KB loads + 6 MFMAs.
// blocks [512,2560): focal | [2560,3072): circ | [3072,5120): consensus
__global__ __launch_bounds__(256) void fused_kernel(
    const float* __restrict__ logits, const int* __restrict__ target,
    const float* __restrict__ masks, const float* __restrict__ preds,
    float* __restrict__ ws) {
  __shared__ float red[32];
  const int bid = blockIdx.x;
  const int tid = threadIdx.x;
  const int lane = tid & 63;
  const int wid = tid >> 6;

  if (bid < 512) {
    // ================= sim =================
    const int rt = bid >> 4;        // 0..31, rows rt*32
    const int ct = bid & 15;        // 0..15, cols ct*64
    const int wr = wid >> 1, wc = wid & 1;
    const int l15 = lane & 15;
    const int hi8 = lane >> 4;
    const char* HI = (const char*)ws + WS_HI_B;
    const char* LO = (const char*)ws + WS_LO_B;
    const int rga = rt * 2 + wr;          // A row-group (16 rows)
    const int rgb = ct * 4 + wc * 2;      // B row-groups rgb, rgb+1
    const int lb16 = lane * 16;

    f32x4 acc0 = {0.f, 0.f, 0.f, 0.f};
    f32x4 acc1 = {0.f, 0.f, 0.f, 0.f};

#pragma unroll 2
    for (int kb = 0; kb < 16; kb++) {
      const char* pA = HI + (rga * 16 + kb) * 1024 + lb16;
      const char* qA = LO + (rga * 16 + kb) * 1024 + lb16;
      const char* pB0 = HI + (rgb * 16 + kb) * 1024 + lb16;
      const char* qB0 = LO + (rgb * 16 + kb) * 1024 + lb16;
      const char* pB1 = HI + ((rgb + 1) * 16 + kb) * 1024 + lb16;
      const char* qB1 = LO + ((rgb + 1) * 16 + kb) * 1024 + lb16;
      bf16x8 ah = *(const bf16x8*)pA;
      bf16x8 al = *(const bf16x8*)qA;
      bf16x8 bh0 = *(const bf16x8*)pB0;
      bf16x8 bl0 = *(const bf16x8*)qB0;
      bf16x8 bh1 = *(const bf16x8*)pB1;
      bf16x8 bl1 = *(const bf16x8*)qB1;
      acc0 = __builtin_amdgcn_mfma_f32_16x16x32_bf16(ah, bh0, acc0, 0, 0, 0);
      acc1 = __builtin_amdgcn_mfma_f32_16x16x32_bf16(ah, bh1, acc1, 0, 0, 0);
      acc0 = __builtin_amdgcn_mfma_f32_16x16x32_bf16(ah, bl0, acc0, 0, 0, 0);
      acc1 = __builtin_amdgcn_mfma_f32_16x16x32_bf16(ah, bl1, acc1, 0, 0, 0);
      acc0 = __builtin_amdgcn_mfma_f32_16x16x32_bf16(al, bh0, acc0, 0, 0, 0);
      acc1 = __builtin_amdgcn_mfma_f32_16x16x32_bf16(al, bh1, acc1, 0, 0, 0);
    }

    // epilogue: D row=(lane>>4)*4+q, col=lane&15 per 16x16 tile
    float2* part = (float2*)(ws + WS_PART);
    int c0 = ct * 64 + wc * 32 + l15;
    int c1 = c0 + 16;
#pragma unroll
    for (int q = 0; q < 4; q++) {
      int row = rt * 32 + wr * 16 + hi8 * 4 + q;
      int pc = (row + 512) & 1023;
      float v0 = acc0[q], v1 = acc1[q];
      if (c0 == pc) ws[WS_POS + row] = v0;
      if (c1 == pc) ws[WS_POS + row] = v1;
      if (c0 == row) v0 = -1e30f;
      if (c1 == row) v1 = -1e30f;
      float m = fmaxf(v0, v1);
      float s = __expf(v0 - m) + __expf(v1 - m);
#pragma unroll
      for (int d = 1; d < 16; d <<= 1) {
        float mo = __shfl_xor(m, d), so = __shfl_xor(s, d);
        float nm = fmaxf(m, mo);
        s = s * __expf(m - nm) + so * __expf(mo - nm);
        m = nm;
      }
      if (l15 == 0) part[row * 32 + ct * 2 + wc] = make_float2(m, s);
    }
    return;
  }

  const int bid2 = bid - 512;

  if (bid2 < 2048) {
    // ================= focal =================
    int t = bid2 * 256 + tid;
    int p4 = t * 4;
    int b = p4 >> 16;
    int hw = p4 & 65535;
    const float* lb = logits + (b << 19) + hw;
    float4 x0 = *(const float4*)(lb + (0 << 16));
    float4 x1 = *(const float4*)(lb + (1 << 16));
    float4 x2 = *(const float4*)(lb + (2 << 16));
    float4 x3 = *(const float4*)(lb + (3 << 16));
    float4 x4 = *(const float4*)(lb + (4 << 16));
    float4 x5 = *(const float4*)(lb + (5 << 16));
    float4 x6 = *(const float4*)(lb + (6 << 16));
    float4 x7 = *(const float4*)(lb + (7 << 16));
    int4 tg = *(const int4*)(target + p4);
    float acc = 0.0f;
    acc += focal_px(x0.x, x1.x, x2.x, x3.x, x4.x, x5.x, x6.x, x7.x, tg.x);
    acc += focal_px(x0.y, x1.y, x2.y, x3.y, x4.y, x5.y, x6.y, x7.y, tg.y);
    acc += focal_px(x0.z, x1.z, x2.z, x3.z, x4.z, x5.z, x6.z, x7.z, tg.z);
    acc += focal_px(x0.w, x1.w, x2.w, x3.w, x4.w, x5.w, x6.w, x7.w, tg.w);
    float v = wave_reduce(acc);
    if (lane == 0) red[wid] = v;
    __syncthreads();
    if (tid == 0) ws[WS_FOCALP + bid2] = red[0] + red[1] + red[2] + red[3];

  } else if (bid2 < 2560) {
    // ================= circularity =================
    int bi = bid2 - 2048;
    int img = bi >> 4;
    int part = bi & 15;
    const float* mS = masks + img * 3 * 65536;
    const float4* m4 = (const float4*)mS;
    float a = 0.0f, ex = 0.0f, ey = 0.0f;
#pragma unroll
    for (int i = 0; i < 4; i++) {
      int v = tid + 256 * i;
      int rl = v >> 6;
      int c4 = v & 63;
      int row = part * 16 + rl;
      float4 val = m4[row * 64 + c4];
      a += val.x + val.y + val.z + val.w;
      ey += fabsf(val.y - val.x) + fabsf(val.z - val.y) + fabsf(val.w - val.z);
      if (c4 > 0) ey += fabsf(val.x - mS[row * 256 + c4 * 4 - 1]);
      if (row > 0) {
        float4 u = m4[(row - 1) * 64 + c4];
        ex += fabsf(val.x - u.x) + fabsf(val.y - u.y) +
              fabsf(val.z - u.z) + fabsf(val.w - u.w);
      }
    }
    float ra = wave_reduce(a);
    float rx = wave_reduce(ex);
    float ry = wave_reduce(ey);
    if (lane == 0) {
      red[wid + 0] = ra; red[wid + 4] = rx; red[wid + 8] = ry;
    }
    __syncthreads();
    if (tid == 0) {
      ws[WS_AREAP + bi] = red[0] + red[1] + red[2] + red[3];
      ws[WS_EXP_ + bi] = red[4] + red[5] + red[6] + red[7];
      ws[WS_EYP_ + bi] = red[8] + red[9] + red[10] + red[11];
    }

  } else {
    // ================= consensus =================
    int b = bid2 - 2560;
    int t = b * 256 + tid;
    const float4* q = (const float4*)preds;
    float4 a0 = q[t];
    float4 a1 = q[t + 524288];
    float4 a2 = q[t + 1048576];
    float s0 = a0.x + a0.y + a0.z + a0.w;
    float s1 = a1.x + a1.y + a1.z + a1.w;
    float s2 = a2.x + a2.y + a2.z + a2.w;
    float p01 = a0.x * a1.x + a0.y * a1.y + a0.z * a1.z + a0.w * a1.w;
    float p02 = a0.x * a2.x + a0.y * a2.y + a0.z * a2.z + a0.w * a2.w;
    float p12 = a1.x * a2.x + a1.y * a2.y + a1.z * a2.z + a1.w * a2.w;
    float r0 = wave_reduce(s0);
    float r1 = wave_reduce(s1);
    float r2 = wave_reduce(s2);
    float r3 = wave_reduce(p01);
    float r4 = wave_reduce(p02);
    float r5 = wave_reduce(p12);
    if (lane == 0) {
      red[wid + 0] = r0; red[wid + 4] = r1; red[wid + 8] = r2;
      red[wid + 12] = r3; red[wid + 16] = r4; red[wid + 20] = r5;
    }
    __syncthreads();
    if (tid == 0) {
#pragma unroll
      for (int k = 0; k < 6; k++)
        ws[WS_CONSP + k * 2048 + b] =
            red[k * 4] + red[k * 4 + 1] + red[k * 4 + 2] + red[k * 4 + 3];
    }
  }
}

__global__ __launch_bounds__(1024) void final_kernel(float* __restrict__ ws,
                                                     float* __restrict__ out) {
  __shared__ float red[16][8];
  __shared__ float li_s[32];
  int r = threadIdx.x;  // 0..1023
  int lane = r & 63, wid = r >> 6;

  float v[8];
  // ---- contrastive LSE merge over 32 col-groups ----
  const float2* part = (const float2*)(ws + WS_PART);
  float M = -1e30f, S = 0.0f;
#pragma unroll
  for (int ctl = 0; ctl < 32; ctl++) {
    float2 p = part[r * 32 + ctl];
    float nm = fmaxf(M, p.x);
    S = S * __expf(M - nm) + p.y * __expf(p.x - nm);
    M = nm;
  }
  v[0] = (M + __logf(S)) - ws[WS_POS + r];
  // ---- focal partials ----
  v[1] = ws[WS_FOCALP + r] + ws[WS_FOCALP + r + 1024];
  // ---- consensus partials ----
#pragma unroll
  for (int k = 0; k < 6; k++) {
    const float* p = ws + WS_CONSP + k * 2048;
    v[2 + k] = p[r] + p[r + 1024];
  }
#pragma unroll
  for (int k = 0; k < 8; k++) {
    v[k] = wave_reduce(v[k]);
    if (lane == 0) red[wid][k] = v[k];
  }

  // ---- circularity: 32 imgs x 16 parts ----
  if (r < 512) {
    float a = ws[WS_AREAP + r];
    float ex = ws[WS_EXP_ + r];
    float ey = ws[WS_EYP_ + r];
#pragma unroll
    for (int d = 1; d < 16; d <<= 1) {
      a += __shfl_xor(a, d);
      ex += __shfl_xor(ex, d);
      ey += __shfl_xor(ey, d);
    }
    if ((r & 15) == 0) {
      float per = ex + ey;
      float dd = fmaxf(per, 1e-12f);
      float c = 12.566370614359172f * a / (dd * dd);
      li_s[r >> 4] = (a > 0.0f && per > 0.0f) ? (c - 1.0f) * (c - 1.0f) : 0.0f;
    }
  }
  __syncthreads();

  if (r == 0) {
    float tot[8];
#pragma unroll
    for (int k = 0; k < 8; k++) {
      float t = 0.0f;
#pragma unroll
      for (int i = 0; i < 16; i++) t += red[i][k];
      tot[k] = t;
    }
    float circ = 0.0f;
#pragma unroll
    for (int i = 0; i < 32; i++) circ += li_s[i];
    circ = 0.1f * circ / 32.0f;

    float contr = tot[0] / 1024.0f;
    float focal = tot[1] / 2097152.0f;

    float S0 = tot[2], S1 = tot[3], S2 = tot[4];
    float P01 = tot[5], P02 = tot[6], P12 = tot[7];
    float co = 0.0f;
    co += fmaxf(0.6f - P01 / (S0 + S1 - P01 + 1e-6f), 0.0f);
    co += fmaxf(0.6f - P02 / (S0 + S2 - P02 + 1e-6f), 0.0f);
    co += fmaxf(0.6f - P12 / (S1 + S2 - P12 + 1e-6f), 0.0f);
    co *= (1.0f / 3.0f);

    out[0] = focal + 0.5f * contr + circ + 0.3f * co;
  }
}

extern "C" void kernel_launch(void* const* d_in, const int* in_sizes, int n_in,
                              void* d_out, int out_size, void* d_ws, size_t ws_size,
                              hipStream_t stream) {
  const float* logits = (const float*)d_in[0];
  const int* target = (const int*)d_in[1];
  const float* feat = (const float*)d_in[2];
  const float* masks = (const float*)d_in[3];
  const float* preds = (const float*)d_in[4];
  float* ws = (float*)d_ws;
  float* out = (float*)d_out;

  prep_kernel<<<256, 256, 0, stream>>>(feat, ws);
  fused_kernel<<<5120, 256, 0, stream>>>(logits, target, masks, preds, ws);
  final_kernel<<<1, 1024, 0, stream>>>(ws, out);
}